// Round 2
// baseline (250.696 us; speedup 1.0000x reference)
//
#include <hip/hip_runtime.h>

// Problem constants (from reference)
#define BATCH 16384
#define DI 2048      // INPUT_DELAY_SIZE * INPUT_SIZE
#define DO 64        // OUTPUT_DELAY_SIZE * OUTPUT_SIZE
#define IS 64        // INPUT_SIZE

// One WAVE (64 lanes) per batch row; block = 256 threads = 4 rows.
// Lane l owns 8 interleaved float4 chunks of itdl: element k = j*256 + l*4,
// j = 0..7  -> each load is a fully coalesced 1 KB wave transaction, and a
// wave has 8 dwordx4 loads in flight (vs 2 in the block-per-row version).
// No LDS, no __syncthreads: the dot reduction is a 6-step shuffle chain.
__global__ __launch_bounds__(256) void arx_cell_kernel(
    const float* __restrict__ input,   // [B, 64]
    const float* __restrict__ itdl,    // [B, 2048]
    const float* __restrict__ otdl,    // [B, 64]
    const float* __restrict__ iw,      // [2048]
    const float* __restrict__ ow,      // [64]
    const float* __restrict__ bias,    // [1]
    float* __restrict__ out)           // [B] ++ [B*2048] ++ [B*64]
{
    const int t    = threadIdx.x;
    const int lane = t & 63;
    const int row  = blockIdx.x * 4 + (t >> 6);

    const float* it = itdl + (size_t)row * DI;
    float* out0 = out;                              // outputs  [B]
    float* o1   = out + BATCH + (size_t)row * DI;   // itdl_new row
    float* o2   = out + BATCH + (size_t)BATCH * DI  // otdl_new row
                      + (size_t)row * DO;

    // ---- issue all itdl loads first (8 outstanding dwordx4/lane) ----
    float4 v[8];
    #pragma unroll
    for (int j = 0; j < 8; ++j)
        v[j] = *(const float4*)(it + j * 256 + lane * 4);

    // input tail (lanes 0..15 cover input[row][0:64])
    float4 in0 = make_float4(0.f, 0.f, 0.f, 0.f);
    if (lane < 16)
        in0 = *(const float4*)(input + (size_t)row * IS + lane * 4);

    // otdl (one element per lane)
    float oval = otdl[(size_t)row * DO + lane];

    // ---- dot products (iw/ow are hot in L1/L2 across all waves) ----
    float partial = 0.f;
    #pragma unroll
    for (int j = 0; j < 8; ++j) {
        float4 wv = *(const float4*)(iw + j * 256 + lane * 4);
        partial += v[j].x * wv.x + v[j].y * wv.y
                 + v[j].z * wv.z + v[j].w * wv.w;
    }
    partial += oval * ow[lane];

    // ---- itdl_new: shift-by-64, reusing the registers ----
    #pragma unroll
    for (int j = 0; j < 8; ++j) {
        const int k = j * 256 + lane * 4;
        if (j == 0) {
            if (lane < 16) {
                *(float4*)(o1 + (DI - IS) + lane * 4) = in0;   // append input
            } else {
                *(float4*)(o1 + k - IS) = v[j];
            }
        } else {
            *(float4*)(o1 + k - IS) = v[j];
        }
    }

    // ---- otdl_new: shift-by-1 (positions 0..62) ----
    if (lane >= 1) o2[lane - 1] = oval;

    // ---- wave reduction, no LDS / no barrier ----
    #pragma unroll
    for (int off = 32; off > 0; off >>= 1)
        partial += __shfl_down(partial, off, 64);

    if (lane == 0) {
        float a2 = partial + bias[0];
        out0[row]    = a2;   // outputs[row]
        o2[DO - 1]   = a2;   // otdl_new tail
    }
}

extern "C" void kernel_launch(void* const* d_in, const int* in_sizes, int n_in,
                              void* d_out, int out_size, void* d_ws, size_t ws_size,
                              hipStream_t stream) {
    const float* input = (const float*)d_in[0];
    const float* itdl  = (const float*)d_in[1];
    const float* otdl  = (const float*)d_in[2];
    const float* iw    = (const float*)d_in[3];
    const float* ow    = (const float*)d_in[4];
    const float* bias  = (const float*)d_in[5];
    float* out = (float*)d_out;

    arx_cell_kernel<<<BATCH / 4, 256, 0, stream>>>(input, itdl, otdl, iw, ow, bias, out);
}